// Round 10
// baseline (779.955 us; speedup 1.0000x reference)
//
#include <hip/hip_runtime.h>
#include <stdint.h>

typedef short bf16x8 __attribute__((ext_vector_type(8)));
typedef _Float16 f16x8 __attribute__((ext_vector_type(8)));
typedef float f32x4 __attribute__((ext_vector_type(4)));
typedef unsigned int u32x2_t __attribute__((ext_vector_type(2)));
typedef unsigned int u32x4_t __attribute__((ext_vector_type(4)));
typedef unsigned int u32;
typedef unsigned short u16;
typedef unsigned char u8;
typedef unsigned long long u64;

#define NB  16
#define SEQ 2048
#define DD  1024
#define BM  32
#define KVB 32
#define NWAVE 8
#define NKB (SEQ / KVB)

// d_ws layout (bytes):
//   QH  [b][kv][d] f16 (round-to-nearest)                    : 64 MB
//   QT2 [b][kb][d][16 u32] kv-pair-interleaved f16 Q^T tiles : 64 MB
#define WS_QH  0ULL
#define WS_QT2 (64ULL << 20)
#define WS_NEED (128ULL << 20)

union HF { u32 u[4]; u32x4_t u4; f16x8 v; };

__device__ __forceinline__ f32x4 z4() {
  f32x4 v; v[0] = 0.f; v[1] = 0.f; v[2] = 0.f; v[3] = 0.f; return v;
}
__device__ __forceinline__ float h16(float x) {
  return __uint_as_float((__float_as_uint(x) + 0x1000u) & 0xFFFFE000u);
}
__device__ __forceinline__ u32 packh(float a, float b) {
  auto t = __builtin_amdgcn_cvt_pkrtz(a, b);
  return *(u32*)&t;
}
__device__ __forceinline__ f32x4 mfma16(f16x8 a, f16x8 b, f32x4 c) {
  return __builtin_amdgcn_mfma_f32_16x16x32_f16(a, b, c, 0, 0, 0);
}
// LDS-ordering barrier only; VMEM loads stay in flight (no vmcnt drain).
__device__ __forceinline__ void wg_barrier() {
  asm volatile("s_waitcnt lgkmcnt(0)" ::: "memory");
  __builtin_amdgcn_s_barrier();
  asm volatile("" ::: "memory");
}

// ---------------- prepass: q -> QH (f16 rows) + QT2 (kb-blocked transposed) ----------------
__global__ __launch_bounds__(256)
void prepass(const float* __restrict__ Q, u16* __restrict__ QH, u32* __restrict__ QT2) {
  __shared__ u16 hl[32][72];
  const int t = threadIdx.x;
  const int bidx = (int)blockIdx.x;          // b*1024 + kvb*16 + db
  const int db = bidx & 15, kvb = (bidx >> 4) & 63, b = bidx >> 10;
  const int r = t >> 3, dcc = (t & 7) * 8;
  const int kv = kvb * 32 + r;
  const size_t row = (size_t)(b * SEQ + kv) * DD + db * 64 + dcc;
  f32x4 v0 = ((const f32x4*)(Q + row))[0];
  f32x4 v1 = ((const f32x4*)(Q + row))[1];
  float e[8] = { v0[0], v0[1], v0[2], v0[3], v1[0], v1[1], v1[2], v1[3] };
  u32x4_t hw;
#pragma unroll
  for (int j = 0; j < 4; ++j)
    hw[j] = packh(h16(e[2 * j]), h16(e[2 * j + 1]));
  *(u32x4_t*)(QH + row) = hw;
#pragma unroll
  for (int j = 0; j < 4; ++j) {
    hl[r][dcc + 2 * j]     = (u16)(hw[j] & 0xffffu);
    hl[r][dcc + 2 * j + 1] = (u16)(hw[j] >> 16);
  }
  __syncthreads();
  const int d = t >> 2, i4 = (t & 3) * 4;
  u32x4_t w;
#pragma unroll
  for (int ii = 0; ii < 4; ++ii) {
    const int i = i4 + ii;
    w[ii] = (u32)hl[i][d] | ((u32)hl[i + 16][d] << 16);  // (kv0+i, kv0+16+i)
  }
  u32* dst = QT2 + (((size_t)(b * 64 + kvb) * 1024) + (db * 64 + d)) * 16 + i4;
  *(u32x4_t*)dst = w;
}

// ---------------- main: (2 kvh x 4 dc) S-split, fused distributed softmax ----------------
__global__ __launch_bounds__(512, 2)
void attn_main(const float* __restrict__ Ag, const u16* __restrict__ QH,
               const u32* __restrict__ QT2, float* __restrict__ Og) {
  __shared__ alignas(16) float sp[2][2][4][32][20];  // [buf][kvh][dc][arow][kv-quad] 40960 B
  __shared__ alignas(16) u32  Plds[2][32][20];       // [buf][arow][pair-word]        5120 B
  __shared__ alignas(16) float crow[2][32];          // per-row rescale factor
  __shared__ alignas(16) float Lrow[32];             // final denominators

  const int tid  = (int)threadIdx.x;
  const int w    = tid >> 6;
  const int lane = tid & 63;
  const int g    = lane >> 4;
  const int m    = lane & 15;
  const int kvh  = w >> 2;        // kv-half for S
  const int dc   = w & 3;         // d-chunk of 256 for S
  const int dw   = w * 128;       // d-chunk of 128 for PV/O
  const int srow = 4 * w + (lane >> 3);   // softmax row (lanes<32)
  const int qc   = lane & 7;              // softmax kv-quad (lanes<32)

  // XCD chunk swizzle (bijective, 1024 = 8*128)
  const int p = (int)blockIdx.x;
  const int l = (p & 7) * 128 + (p >> 3);
  const int b = l >> 6;
  const int ablk = l & 63;

  const float* Abase = Ag + ((size_t)(b * SEQ + ablk * BM)) * DD;
  float*       Ob    = Og + ((size_t)(b * SEQ + ablk * BM)) * DD;
  const u16* Qb = QH + (size_t)(b * SEQ) * DD + dc * 256 + g * 8;
  const u32* Vb = QT2 + (size_t)(b * 64) * 16384 + (size_t)(dw + m) * 16 + g * 4;

  // ---- prologue: A fragments for this wave's 256-d chunk (f16, regs)
  f16x8 ah[2][8];
#pragma unroll
  for (int rt = 0; rt < 2; ++rt) {
#pragma unroll
    for (int kt = 0; kt < 8; ++kt) {
      const float* src = Abase + (size_t)(rt * 16 + m) * DD + dc * 256 + kt * 32 + g * 8;
      f32x4 v0 = ((const f32x4*)src)[0];
      f32x4 v1 = ((const f32x4*)src)[1];
      float e[8] = { v0[0], v0[1], v0[2], v0[3], v1[0], v1[1], v1[2], v1[3] };
      HF fh;
#pragma unroll
      for (int j = 0; j < 4; ++j) fh.u[j] = packh(h16(e[2 * j]), h16(e[2 * j + 1]));
      ah[rt][kt] = fh.v;
    }
  }

  f32x4 oacc[2][8];
#pragma unroll
  for (int mt = 0; mt < 2; ++mt)
#pragma unroll
    for (int nt = 0; nt < 8; ++nt) oacc[mt][nt] = z4();

  float M = -1e30f, L = 0.f;   // per-row state, owner lanes (<32)
  HF q[8];
  u32x4_t bq[8];

  auto LOADQ = [&](int kv0) {
#pragma unroll
    for (int kt = 0; kt < 8; ++kt)
      q[kt].u4 = *(const u32x4_t*)(Qb + (size_t)(kv0 + kvh * 16 + m) * DD + kt * 32);
  };
  auto SSTEP = [&](int buf) {
    f32x4 st0 = z4(), st1 = z4();
#pragma unroll
    for (int kt = 0; kt < 8; ++kt) {
      st0 = mfma16(q[kt].v, ah[0][kt], st0);
      st1 = mfma16(q[kt].v, ah[1][kt], st1);
    }
    *(f32x4*)&sp[buf][kvh][dc][m][g * 4]      = st0;
    *(f32x4*)&sp[buf][kvh][dc][16 + m][g * 4] = st1;
  };
  auto PV = [&](int C) {
    f32x4 cr0 = *(const f32x4*)&crow[C][g * 4];
    f32x4 cr1 = *(const f32x4*)&crow[C][16 + g * 4];
    HF pa0, pa1;
    pa0.u4 = *(const u32x4_t*)&Plds[C][m][g * 4];
    pa1.u4 = *(const u32x4_t*)&Plds[C][16 + m][g * 4];
    bool nr = (cr0[0] != 1.f) | (cr0[1] != 1.f) | (cr0[2] != 1.f) | (cr0[3] != 1.f) |
              (cr1[0] != 1.f) | (cr1[1] != 1.f) | (cr1[2] != 1.f) | (cr1[3] != 1.f);
    if (__any(nr)) {
#pragma unroll
      for (int nt = 0; nt < 8; ++nt)
#pragma unroll
        for (int j = 0; j < 4; ++j) {
          oacc[0][nt][j] *= cr0[j];
          oacc[1][nt][j] *= cr1[j];
        }
    }
#pragma unroll
    for (int nt = 0; nt < 8; ++nt) {
      HF bqv; bqv.u4 = bq[nt];
      oacc[0][nt] = mfma16(pa0.v, bqv.v, oacc[0][nt]);
      oacc[1][nt] = mfma16(pa1.v, bqv.v, oacc[1][nt]);
    }
  };

  // ---- pipeline prologue
  LOADQ(0);
  SSTEP(0);
  LOADQ(KVB);
  wg_barrier();

#pragma unroll 1
  for (int kb = 0; kb < NKB; ++kb) {
    const int A = kb & 1;

    // (1) PV(kb-1) — consumes bq loaded last iter, P/crow from last iter's softmax
    if (kb > 0) PV(A ^ 1);

    // (2) issue bq(kb): contiguous 1KB per nt, in flight until next iter's PV
    const u32* vrow = Vb + (size_t)kb * 16384;
#pragma unroll
    for (int nt = 0; nt < 8; ++nt)
      bq[nt] = *(const u32x4_t*)(vrow + nt * 256);

    // (3) S(kb+1) -> sp[A^1]; prefetch Q(kb+2)
    if (kb + 1 < NKB) {
      SSTEP(A ^ 1);
      if (kb + 2 < NKB) LOADQ((kb + 2) * KVB);
    }

    // (4) fused distributed reduce+softmax(kb): lanes<32, one (row, kv-quad) each
    if (lane < 32) {
      f32x4 s4 = *(const f32x4*)&sp[A][qc >> 2][0][srow][(qc & 3) * 4];
#pragma unroll
      for (int dcc = 1; dcc < 4; ++dcc) {
        f32x4 t = *(const f32x4*)&sp[A][qc >> 2][dcc][srow][(qc & 3) * 4];
        s4 += t;
      }
      float mq = fmaxf(fmaxf(s4[0], s4[1]), fmaxf(s4[2], s4[3]));
      mq = fmaxf(mq, __shfl_xor(mq, 1));
      mq = fmaxf(mq, __shfl_xor(mq, 2));
      mq = fmaxf(mq, __shfl_xor(mq, 4));
      const float Mn = fmaxf(M, mq);
      const float c = __expf(M - Mn);     // == 1.0 exactly when M unchanged
      const float p0 = __expf(s4[0] - Mn);
      const float p1 = __expf(s4[1] - Mn);
      const float p2 = __expf(s4[2] - Mn);
      const float p3 = __expf(s4[3] - Mn);
      float rq = (p0 + p1) + (p2 + p3);
      rq += __shfl_xor(rq, 1);
      rq += __shfl_xor(rq, 2);
      rq += __shfl_xor(rq, 4);
      L = L * c + rq;
      M = Mn;
      const float q0 = __shfl_xor(p0, 4);
      const float q1 = __shfl_xor(p1, 4);
      const float q2 = __shfl_xor(p2, 4);
      const float q3 = __shfl_xor(p3, 4);
      if (qc < 4) {   // kv 0..15 threads pack (kv, kv+16) pairs -> matches QT2 words
        u32x4_t wv;
        wv[0] = packh(p0, q0); wv[1] = packh(p1, q1);
        wv[2] = packh(p2, q2); wv[3] = packh(p3, q3);
        *(u32x4_t*)&Plds[A][srow][qc * 4] = wv;
      }
      if (qc == 0) { crow[A][srow] = c; Lrow[srow] = L; }
    }

    // (5) one barrier: LDS-order only, VMEM stays in flight
    wg_barrier();
  }

  // ---- drain last PV
  PV((NKB - 1) & 1);

  // ---- epilogue: normalize by L and store
  f32x4 L0v = *(const f32x4*)&Lrow[g * 4];
  f32x4 L1v = *(const f32x4*)&Lrow[16 + g * 4];
  f32x4 i0, i1;
#pragma unroll
  for (int j = 0; j < 4; ++j) { i0[j] = 1.f / L0v[j]; i1[j] = 1.f / L1v[j]; }
#pragma unroll
  for (int mt = 0; mt < 2; ++mt)
#pragma unroll
    for (int nt = 0; nt < 8; ++nt)
#pragma unroll
      for (int j = 0; j < 4; ++j) {
        const int r  = mt * 16 + g * 4 + j;
        const int dcol = dw + nt * 16 + m;
        Ob[(size_t)r * DD + dcol] = oacc[mt][nt][j] * (mt ? i1[j] : i0[j]);
      }
}

// ---------------- fallback (round-2 kernel, proven) ----------------
#define FB_VSTR 18
__device__ __forceinline__ u32 fb_rn16(u32 bb) { return (bb + 0x8000u) & 0xffff0000u; }
__device__ __forceinline__ u32 fb_pack(float x0, float x1) {
  return fb_rn16(__float_as_uint(x1)) | (fb_rn16(__float_as_uint(x0)) >> 16);
}
union FbFrag { u32 u[4]; u32x4_t u4; bf16x8 v; };
__device__ __forceinline__ void fb_cvt(const float* x, FbFrag& fh, FbFrag& fl) {
#pragma unroll
  for (int i = 0; i < 4; ++i) {
    float x0 = x[2 * i], x1 = x[2 * i + 1];
    u32 h0 = fb_rn16(__float_as_uint(x0));
    u32 h1 = fb_rn16(__float_as_uint(x1));
    fh.u[i] = h1 | (h0 >> 16);
    fl.u[i] = fb_pack(x0 - __uint_as_float(h0), x1 - __uint_as_float(h1));
  }
}

__global__ __launch_bounds__(512, 2)
void attn_fb(const float* __restrict__ Qg, const float* __restrict__ Ag,
             float* __restrict__ Og) {
  __shared__ u32 vT[8][128 * FB_VSTR];
  __shared__ float sp[8][32][36];
  __shared__ float ssum[32][36];
  const int tid = threadIdx.x, w = tid >> 6, lane = tid & 63, g = lane >> 4, m = lane & 15;
  const int bid = (int)blockIdx.x, b = bid >> 6, ablk = bid & 63, dw = w * 128;
  const float* Qb = Qg + (size_t)b * SEQ * DD;
  const float* Abase = Ag + ((size_t)b * SEQ + ablk * 32) * DD;
  float* Ob = Og + ((size_t)b * SEQ + ablk * 32) * DD;
  FbFrag ah[2][4], al[2][4];
#pragma unroll
  for (int rt = 0; rt < 2; ++rt)
#pragma unroll
    for (int kt = 0; kt < 4; ++kt) {
      const float* src = Abase + (size_t)(rt * 16 + m) * DD + dw + kt * 32 + g * 8;
      f32x4 v0 = ((const f32x4*)src)[0], v1 = ((const f32x4*)src)[1];
      float x[8];
#pragma unroll
      for (int i = 0; i < 4; ++i) { x[i] = v0[i]; x[4 + i] = v1[i]; }
      fb_cvt(x, ah[rt][kt], al[rt][kt]);
    }
  f32x4 oacc[2][8];
#pragma unroll
  for (int mt = 0; mt < 2; ++mt)
#pragma unroll
    for (int nt = 0; nt < 8; ++nt) oacc[mt][nt] = z4();
  float M0 = -1e30f, M1 = -1e30f, L0 = 0.f, L1 = 0.f;
  u32* vTw = &vT[w][0];
#pragma unroll 1
  for (int kb = 0; kb < NKB; ++kb) {
    const int kv0 = kb * KVB;
    f32x4 st[2][2];
#pragma unroll
    for (int ct = 0; ct < 2; ++ct)
#pragma unroll
      for (int rt = 0; rt < 2; ++rt) st[ct][rt] = z4();
#pragma unroll
    for (int kt = 0; kt < 4; ++kt) {
      FbFrag qh[2], ql[2];
#pragma unroll
      for (int kvt = 0; kvt < 2; ++kvt) {
        const float* src = Qb + (size_t)(kv0 + kvt * 16 + m) * DD + dw + kt * 32 + g * 8;
        f32x4 v0 = ((const f32x4*)src)[0], v1 = ((const f32x4*)src)[1];
        float x[8];
#pragma unroll
        for (int i = 0; i < 4; ++i) { x[i] = v0[i]; x[4 + i] = v1[i]; }
        fb_cvt(x, qh[kvt], ql[kvt]);
      }
      const int dbase = kt * 32 + g * 8;
#pragma unroll
      for (int i = 0; i < 4; ++i) {
        u32 we = (qh[1].u[i] << 16) | (qh[0].u[i] & 0xffffu);
        u32 wo = (qh[1].u[i] & 0xffff0000u) | (qh[0].u[i] >> 16);
        vTw[(dbase + 2 * i) * FB_VSTR + m] = we;
        vTw[(dbase + 2 * i + 1) * FB_VSTR + m] = wo;
      }
#pragma unroll
      for (int ct = 0; ct < 2; ++ct)
#pragma unroll
        for (int rt = 0; rt < 2; ++rt) {
          st[ct][rt] = __builtin_amdgcn_mfma_f32_16x16x32_bf16(qh[ct].v, ah[rt][kt].v, st[ct][rt], 0, 0, 0);
          st[ct][rt] = __builtin_amdgcn_mfma_f32_16x16x32_bf16(qh[ct].v, al[rt][kt].v, st[ct][rt], 0, 0, 0);
          st[ct][rt] = __builtin_amdgcn_mfma_f32_16x16x32_bf16(ql[ct].v, ah[rt][kt].v, st[ct][rt], 0, 0, 0);
        }
    }
#pragma unroll
    for (int ct = 0; ct < 2; ++ct)
#pragma unroll
      for (int rt = 0; rt < 2; ++rt)
        *(f32x4*)&sp[w][rt * 16 + m][ct * 16 + g * 4] = st[ct][rt];
    __syncthreads();
#pragma unroll
    for (int rep = 0; rep < 2; ++rep) {
      const int pp = tid + rep * 512;
      const int r = pp >> 5, c = pp & 31;
      float acc = 0.f;
#pragma unroll
      for (int ww = 0; ww < 8; ++ww) acc += sp[ww][r][c];
      ssum[r][c] = acc;
    }
    __syncthreads();
    f32x4 sv[2][2];
#pragma unroll
    for (int ct = 0; ct < 2; ++ct)
#pragma unroll
      for (int rt = 0; rt < 2; ++rt)
        sv[ct][rt] = *(const f32x4*)&ssum[rt * 16 + m][ct * 16 + g * 4];
    float mx0 = -1e30f, mx1 = -1e30f;
#pragma unroll
    for (int ct = 0; ct < 2; ++ct)
#pragma unroll
      for (int j = 0; j < 4; ++j) {
        mx0 = fmaxf(mx0, sv[ct][0][j]);
        mx1 = fmaxf(mx1, sv[ct][1][j]);
      }
    mx0 = fmaxf(mx0, __shfl_xor(mx0, 16));
    mx0 = fmaxf(mx0, __shfl_xor(mx0, 32));
    mx1 = fmaxf(mx1, __shfl_xor(mx1, 16));
    mx1 = fmaxf(mx1, __shfl_xor(mx1, 32));
    if (__any((mx0 > M0) | (mx1 > M1))) {
      const float nM0 = fmaxf(M0, mx0), nM1 = fmaxf(M1, mx1);
      const float c0 = __expf(M0 - nM0), c1 = __expf(M1 - nM1);
      M0 = nM0; M1 = nM1; L0 *= c0; L1 *= c1;
      f32x4 cr0, cr1;
#pragma unroll
      for (int j = 0; j < 4; ++j) { cr0[j] = __shfl(c0, g * 4 + j); cr1[j] = __shfl(c1, g * 4 + j); }
#pragma unroll
      for (int nt = 0; nt < 8; ++nt)
#pragma unroll
        for (int j = 0; j < 4; ++j) { oacc[0][nt][j] *= cr0[j]; oacc[1][nt][j] *= cr1[j]; }
    }
    f32x4 p00, p10, p01, p11;
#pragma unroll
    for (int j = 0; j < 4; ++j) {
      p00[j] = __expf(sv[0][0][j] - M0);
      p10[j] = __expf(sv[1][0][j] - M0);
      p01[j] = __expf(sv[0][1][j] - M1);
      p11[j] = __expf(sv[1][1][j] - M1);
    }
    float rs0 = 0.f, rs1 = 0.f;
#pragma unroll
    for (int j = 0; j < 4; ++j) { rs0 += p00[j] + p10[j]; rs1 += p01[j] + p11[j]; }
    rs0 += __shfl_xor(rs0, 16); rs0 += __shfl_xor(rs0, 32);
    rs1 += __shfl_xor(rs1, 16); rs1 += __shfl_xor(rs1, 32);
    L0 += rs0; L1 += rs1;
    FbFrag pa0, pa1;
#pragma unroll
    for (int j = 0; j < 4; ++j) {
      pa0.u[j] = fb_pack(p00[j], p10[j]);
      pa1.u[j] = fb_pack(p01[j], p11[j]);
    }
#pragma unroll
    for (int nt = 0; nt < 8; ++nt) {
      const u32* src = &vTw[(nt * 16 + m) * FB_VSTR + g * 4];
      FbFrag bqv;
      *(u32x2_t*)&bqv.u[0] = *(const u32x2_t*)&src[0];
      *(u32x2_t*)&bqv.u[2] = *(const u32x2_t*)&src[2];
      oacc[0][nt] = __builtin_amdgcn_mfma_f32_16x16x32_bf16(pa0.v, bqv.v, oacc[0][nt], 0, 0, 0);
      oacc[1][nt] = __builtin_amdgcn_mfma_f32_16x16x32_bf16(pa1.v, bqv.v, oacc[1][nt], 0, 0, 0);
    }
  }
  f32x4 i0, i1;
#pragma unroll
  for (int j = 0; j < 4; ++j) {
    i0[j] = 1.f / __shfl(L0, g * 4 + j);
    i1[j] = 1.f / __shfl(L1, g * 4 + j);
  }
#pragma unroll
  for (int mt = 0; mt < 2; ++mt)
#pragma unroll
    for (int nt = 0; nt < 8; ++nt)
#pragma unroll
      for (int j = 0; j < 4; ++j) {
        const int r = mt * 16 + g * 4 + j;
        const int dcol = dw + nt * 16 + m;
        Ob[(size_t)r * DD + dcol] = oacc[mt][nt][j] * (mt ? i1[j] : i0[j]);
      }
}

extern "C" void kernel_launch(void* const* d_in, const int* in_sizes, int n_in,
                              void* d_out, int out_size, void* d_ws, size_t ws_size,
                              hipStream_t stream) {
  const float* q = (const float*)d_in[0];
  const float* a = (const float*)d_in[1];
  float* o = (float*)d_out;
  if (ws_size >= WS_NEED) {
    char* ws = (char*)d_ws;
    u16* qh  = (u16*)(ws + WS_QH);
    u32* qt2 = (u32*)(ws + WS_QT2);
    prepass<<<NB * 64 * 16, 256, 0, stream>>>(q, qh, qt2);
    attn_main<<<NB * (SEQ / BM), 512, 0, stream>>>(a, qh, qt2, o);
  } else {
    attn_fb<<<NB * (SEQ / 32), 512, 0, stream>>>(q, a, o);
  }
  (void)in_sizes; (void)n_in; (void)out_size;
}

// Round 11
// 765.124 us; speedup vs baseline: 1.0194x; 1.0194x over previous
//
#include <hip/hip_runtime.h>
#include <stdint.h>

typedef short bf16x8 __attribute__((ext_vector_type(8)));
typedef _Float16 f16x8 __attribute__((ext_vector_type(8)));
typedef float f32x4 __attribute__((ext_vector_type(4)));
typedef unsigned int u32x2_t __attribute__((ext_vector_type(2)));
typedef unsigned int u32x4_t __attribute__((ext_vector_type(4)));
typedef unsigned int u32;
typedef unsigned short u16;
typedef unsigned char u8;
typedef unsigned long long u64;

#define NB  16
#define SEQ 2048
#define DD  1024
#define BM  32
#define KVB 32
#define NKB (SEQ / KVB)

// d_ws layout (bytes):
//   QH  [b][kv][d] f16 (round-to-nearest)                    : 64 MB
//   QT2 [b][kb][d][16 u32] kv-pair-interleaved f16 Q^T tiles : 64 MB
#define WS_QH  0ULL
#define WS_QT2 (64ULL << 20)
#define WS_NEED (128ULL << 20)

union HF { u32 u[4]; u32x4_t u4; f16x8 v; };

__device__ __forceinline__ f32x4 z4() {
  f32x4 v; v[0] = 0.f; v[1] = 0.f; v[2] = 0.f; v[3] = 0.f; return v;
}
__device__ __forceinline__ float h16(float x) {
  return __uint_as_float((__float_as_uint(x) + 0x1000u) & 0xFFFFE000u);
}
__device__ __forceinline__ u32 packh(float a, float b) {
  auto t = __builtin_amdgcn_cvt_pkrtz(a, b);
  return *(u32*)&t;
}
__device__ __forceinline__ f32x4 mfma16(f16x8 a, f16x8 b, f32x4 c) {
  return __builtin_amdgcn_mfma_f32_16x16x32_f16(a, b, c, 0, 0, 0);
}
// LDS-ordering barrier only; VMEM loads stay in flight (no vmcnt drain).
__device__ __forceinline__ void wg_barrier() {
  asm volatile("s_waitcnt lgkmcnt(0)" ::: "memory");
  __builtin_amdgcn_s_barrier();
  asm volatile("" ::: "memory");
}

// ---------------- prepass: q -> QH (f16 rows) + QT2 (kb-blocked transposed) ----------------
__global__ __launch_bounds__(256)
void prepass(const float* __restrict__ Q, u16* __restrict__ QH, u32* __restrict__ QT2) {
  __shared__ u16 hl[32][72];
  const int t = threadIdx.x;
  const int bidx = (int)blockIdx.x;          // b*1024 + kvb*16 + db
  const int db = bidx & 15, kvb = (bidx >> 4) & 63, b = bidx >> 10;
  const int r = t >> 3, dcc = (t & 7) * 8;
  const int kv = kvb * 32 + r;
  const size_t row = (size_t)(b * SEQ + kv) * DD + db * 64 + dcc;
  f32x4 v0 = ((const f32x4*)(Q + row))[0];
  f32x4 v1 = ((const f32x4*)(Q + row))[1];
  float e[8] = { v0[0], v0[1], v0[2], v0[3], v1[0], v1[1], v1[2], v1[3] };
  u32x4_t hw;
#pragma unroll
  for (int j = 0; j < 4; ++j)
    hw[j] = packh(h16(e[2 * j]), h16(e[2 * j + 1]));
  *(u32x4_t*)(QH + row) = hw;
#pragma unroll
  for (int j = 0; j < 4; ++j) {
    hl[r][dcc + 2 * j]     = (u16)(hw[j] & 0xffffu);
    hl[r][dcc + 2 * j + 1] = (u16)(hw[j] >> 16);
  }
  __syncthreads();
  const int d = t >> 2, i4 = (t & 3) * 4;
  u32x4_t w;
#pragma unroll
  for (int ii = 0; ii < 4; ++ii) {
    const int i = i4 + ii;
    w[ii] = (u32)hl[i][d] | ((u32)hl[i + 16][d] << 16);  // (kv0+i, kv0+16+i)
  }
  u32* dst = QT2 + (((size_t)(b * 64 + kvb) * 1024) + (db * 64 + d)) * 16 + i4;
  *(u32x4_t*)dst = w;
}

// ---------------- main: producer/consumer wave specialization (8 PV + 4 S waves) ----------------
__global__ __launch_bounds__(768, 3)
void attn_main(const float* __restrict__ Ag, const u16* __restrict__ QH,
               const u32* __restrict__ QT2, float* __restrict__ Og) {
  __shared__ alignas(16) float sp[2][4][32][36];   // [buf][sw][arow][kv] partial S^T (36864 B)
  __shared__ alignas(16) u32  Plds[2][32][20];     // [buf][arow][pair-word]           (5120 B)
  __shared__ alignas(16) float crow[2][32];        // per-row rescale factor
  __shared__ alignas(16) float Lrow[32];           // running denominators

  const int tid  = (int)threadIdx.x;
  const int w    = tid >> 6;
  const int lane = tid & 63;
  const int g    = lane >> 4;
  const int m    = lane & 15;

  // XCD chunk swizzle (bijective, 1024 = 8*128)
  const int p = (int)blockIdx.x;
  const int l = (p & 7) * 128 + (p >> 3);
  const int b = l >> 6;
  const int ablk = l & 63;

  const float* Abase = Ag + ((size_t)(b * SEQ + ablk * BM)) * DD;
  float*       Ob    = Og + ((size_t)(b * SEQ + ablk * BM)) * DD;

  if (w >= 8) {
    // ================= S waves (producers): wave sw covers d-chunk [256*sw, 256*sw+256) =================
    const int sw = w - 8;
    const u16* Qb = QH + (size_t)(b * SEQ) * DD + sw * 256 + g * 8;

    f16x8 ah[2][8];
#pragma unroll
    for (int rt = 0; rt < 2; ++rt) {
#pragma unroll
      for (int kt = 0; kt < 8; ++kt) {
        const float* src = Abase + (size_t)(rt * 16 + m) * DD + sw * 256 + kt * 32 + g * 8;
        f32x4 v0 = ((const f32x4*)src)[0];
        f32x4 v1 = ((const f32x4*)src)[1];
        float e[8] = { v0[0], v0[1], v0[2], v0[3], v1[0], v1[1], v1[2], v1[3] };
        HF fh;
#pragma unroll
        for (int j = 0; j < 4; ++j) fh.u[j] = packh(h16(e[2 * j]), h16(e[2 * j + 1]));
        ah[rt][kt] = fh.v;
      }
    }

    HF q[2][8];
    auto LOADQ = [&](int kv0) {
#pragma unroll
      for (int ct = 0; ct < 2; ++ct)
#pragma unroll
        for (int kt = 0; kt < 8; ++kt)
          q[ct][kt].u4 = *(const u32x4_t*)(Qb + (size_t)(kv0 + ct * 16 + m) * DD + kt * 32);
    };
    auto SSTEP = [&](int buf) {
      f32x4 st[2][2];
#pragma unroll
      for (int ct = 0; ct < 2; ++ct)
#pragma unroll
        for (int rt = 0; rt < 2; ++rt) st[ct][rt] = z4();
#pragma unroll
      for (int kt = 0; kt < 8; ++kt)
#pragma unroll
        for (int ct = 0; ct < 2; ++ct) {
          st[ct][0] = mfma16(q[ct][kt].v, ah[0][kt], st[ct][0]);
          st[ct][1] = mfma16(q[ct][kt].v, ah[1][kt], st[ct][1]);
        }
#pragma unroll
      for (int ct = 0; ct < 2; ++ct)
#pragma unroll
        for (int rt = 0; rt < 2; ++rt)
          *(f32x4*)&sp[buf][sw][rt * 16 + m][ct * 16 + g * 4] = st[ct][rt];
    };

    LOADQ(0);
    SSTEP(0);
    LOADQ(KVB);
    wg_barrier();                       // #0

#pragma unroll 1
    for (int kb = 0; kb < NKB; ++kb) {
      if (kb + 1 < NKB) {
        SSTEP((kb + 1) & 1);
        if (kb + 2 < NKB) LOADQ((kb + 2) * KVB);
      }
      wg_barrier();                     // #kb+1
    }
  } else {
    // ================= PV waves (consumers): wave w owns O d-chunk [128*w, 128*w+128) =================
    const int dw = w * 128;
    const int srow = 4 * w + (lane >> 3);   // softmax row (lanes<32)
    const int qc   = lane & 7;              // softmax kv-quad (lanes<32)
    const u32* Vb = QT2 + (size_t)(b * 64) * 16384 + (size_t)(dw + m) * 16 + g * 4;

    f32x4 oacc[2][8];
#pragma unroll
    for (int mt = 0; mt < 2; ++mt)
#pragma unroll
      for (int nt = 0; nt < 8; ++nt) oacc[mt][nt] = z4();
    float M = -1e30f, L = 0.f;
    u32x4_t bq[8];

    auto PV = [&](int C) {
      f32x4 cr0 = *(const f32x4*)&crow[C][g * 4];
      f32x4 cr1 = *(const f32x4*)&crow[C][16 + g * 4];
      HF pa0, pa1;
      pa0.u4 = *(const u32x4_t*)&Plds[C][m][g * 4];
      pa1.u4 = *(const u32x4_t*)&Plds[C][16 + m][g * 4];
      bool nr = (cr0[0] != 1.f) | (cr0[1] != 1.f) | (cr0[2] != 1.f) | (cr0[3] != 1.f) |
                (cr1[0] != 1.f) | (cr1[1] != 1.f) | (cr1[2] != 1.f) | (cr1[3] != 1.f);
      if (__any(nr)) {
#pragma unroll
        for (int nt = 0; nt < 8; ++nt)
#pragma unroll
          for (int j = 0; j < 4; ++j) {
            oacc[0][nt][j] *= cr0[j];
            oacc[1][nt][j] *= cr1[j];
          }
      }
#pragma unroll
      for (int nt = 0; nt < 8; ++nt) {
        HF bqv; bqv.u4 = bq[nt];
        oacc[0][nt] = mfma16(pa0.v, bqv.v, oacc[0][nt]);
        oacc[1][nt] = mfma16(pa1.v, bqv.v, oacc[1][nt]);
      }
    };

    wg_barrier();                       // #0

#pragma unroll 1
    for (int kb = 0; kb < NKB; ++kb) {
      const int A = kb & 1;

      if (kb > 0) PV(A ^ 1);

      const u32* vrow = Vb + (size_t)kb * 16384;
#pragma unroll
      for (int nt = 0; nt < 8; ++nt)
        bq[nt] = *(const u32x4_t*)(vrow + nt * 256);

      if (lane < 32) {
        f32x4 s4 = *(const f32x4*)&sp[A][0][srow][qc * 4];
#pragma unroll
        for (int sw2 = 1; sw2 < 4; ++sw2) {
          f32x4 t = *(const f32x4*)&sp[A][sw2][srow][qc * 4];
          s4 += t;
        }
        float mq = fmaxf(fmaxf(s4[0], s4[1]), fmaxf(s4[2], s4[3]));
        mq = fmaxf(mq, __shfl_xor(mq, 1));
        mq = fmaxf(mq, __shfl_xor(mq, 2));
        mq = fmaxf(mq, __shfl_xor(mq, 4));
        const float Mn = fmaxf(M, mq);
        const float c = __expf(M - Mn);     // == 1.0 exactly when M unchanged
        const float p0 = __expf(s4[0] - Mn);
        const float p1 = __expf(s4[1] - Mn);
        const float p2 = __expf(s4[2] - Mn);
        const float p3 = __expf(s4[3] - Mn);
        float rq = (p0 + p1) + (p2 + p3);
        rq += __shfl_xor(rq, 1);
        rq += __shfl_xor(rq, 2);
        rq += __shfl_xor(rq, 4);
        L = L * c + rq;
        M = Mn;
        const float q0 = __shfl_xor(p0, 4);
        const float q1 = __shfl_xor(p1, 4);
        const float q2 = __shfl_xor(p2, 4);
        const float q3 = __shfl_xor(p3, 4);
        if (qc < 4) {   // pack (kv, kv+16) pairs -> matches QT2 words
          u32x4_t wv;
          wv[0] = packh(p0, q0); wv[1] = packh(p1, q1);
          wv[2] = packh(p2, q2); wv[3] = packh(p3, q3);
          *(u32x4_t*)&Plds[A][srow][qc * 4] = wv;
        }
        if (qc == 0) { crow[A][srow] = c; Lrow[srow] = L; }
      }

      wg_barrier();                     // #kb+1
    }

    // drain last PV, then normalize and store
    PV((NKB - 1) & 1);

    f32x4 L0v = *(const f32x4*)&Lrow[g * 4];
    f32x4 L1v = *(const f32x4*)&Lrow[16 + g * 4];
    f32x4 i0, i1;
#pragma unroll
    for (int j = 0; j < 4; ++j) { i0[j] = 1.f / L0v[j]; i1[j] = 1.f / L1v[j]; }
#pragma unroll
    for (int mt = 0; mt < 2; ++mt)
#pragma unroll
      for (int nt = 0; nt < 8; ++nt)
#pragma unroll
        for (int j = 0; j < 4; ++j) {
          const int r  = mt * 16 + g * 4 + j;
          const int dcol = dw + nt * 16 + m;
          Ob[(size_t)r * DD + dcol] = oacc[mt][nt][j] * (mt ? i1[j] : i0[j]);
        }
  }
}

// ---------------- fallback (round-2 kernel, proven) ----------------
#define FB_VSTR 18
__device__ __forceinline__ u32 fb_rn16(u32 bb) { return (bb + 0x8000u) & 0xffff0000u; }
__device__ __forceinline__ u32 fb_pack(float x0, float x1) {
  return fb_rn16(__float_as_uint(x1)) | (fb_rn16(__float_as_uint(x0)) >> 16);
}
union FbFrag { u32 u[4]; u32x4_t u4; bf16x8 v; };
__device__ __forceinline__ void fb_cvt(const float* x, FbFrag& fh, FbFrag& fl) {
#pragma unroll
  for (int i = 0; i < 4; ++i) {
    float x0 = x[2 * i], x1 = x[2 * i + 1];
    u32 h0 = fb_rn16(__float_as_uint(x0));
    u32 h1 = fb_rn16(__float_as_uint(x1));
    fh.u[i] = h1 | (h0 >> 16);
    fl.u[i] = fb_pack(x0 - __uint_as_float(h0), x1 - __uint_as_float(h1));
  }
}

__global__ __launch_bounds__(512, 2)
void attn_fb(const float* __restrict__ Qg, const float* __restrict__ Ag,
             float* __restrict__ Og) {
  __shared__ u32 vT[8][128 * FB_VSTR];
  __shared__ float sp[8][32][36];
  __shared__ float ssum[32][36];
  const int tid = threadIdx.x, w = tid >> 6, lane = tid & 63, g = lane >> 4, m = lane & 15;
  const int bid = (int)blockIdx.x, b = bid >> 6, ablk = bid & 63, dw = w * 128;
  const float* Qb = Qg + (size_t)b * SEQ * DD;
  const float* Abase = Ag + ((size_t)b * SEQ + ablk * 32) * DD;
  float* Ob = Og + ((size_t)b * SEQ + ablk * 32) * DD;
  FbFrag ah[2][4], al[2][4];
#pragma unroll
  for (int rt = 0; rt < 2; ++rt)
#pragma unroll
    for (int kt = 0; kt < 4; ++kt) {
      const float* src = Abase + (size_t)(rt * 16 + m) * DD + dw + kt * 32 + g * 8;
      f32x4 v0 = ((const f32x4*)src)[0], v1 = ((const f32x4*)src)[1];
      float x[8];
#pragma unroll
      for (int i = 0; i < 4; ++i) { x[i] = v0[i]; x[4 + i] = v1[i]; }
      fb_cvt(x, ah[rt][kt], al[rt][kt]);
    }
  f32x4 oacc[2][8];
#pragma unroll
  for (int mt = 0; mt < 2; ++mt)
#pragma unroll
    for (int nt = 0; nt < 8; ++nt) oacc[mt][nt] = z4();
  float M0 = -1e30f, M1 = -1e30f, L0 = 0.f, L1 = 0.f;
  u32* vTw = &vT[w][0];
#pragma unroll 1
  for (int kb = 0; kb < NKB; ++kb) {
    const int kv0 = kb * KVB;
    f32x4 st[2][2];
#pragma unroll
    for (int ct = 0; ct < 2; ++ct)
#pragma unroll
      for (int rt = 0; rt < 2; ++rt) st[ct][rt] = z4();
#pragma unroll
    for (int kt = 0; kt < 4; ++kt) {
      FbFrag qh[2], ql[2];
#pragma unroll
      for (int kvt = 0; kvt < 2; ++kvt) {
        const float* src = Qb + (size_t)(kv0 + kvt * 16 + m) * DD + dw + kt * 32 + g * 8;
        f32x4 v0 = ((const f32x4*)src)[0], v1 = ((const f32x4*)src)[1];
        float x[8];
#pragma unroll
        for (int i = 0; i < 4; ++i) { x[i] = v0[i]; x[4 + i] = v1[i]; }
        fb_cvt(x, qh[kvt], ql[kvt]);
      }
      const int dbase = kt * 32 + g * 8;
#pragma unroll
      for (int i = 0; i < 4; ++i) {
        u32 we = (qh[1].u[i] << 16) | (qh[0].u[i] & 0xffffu);
        u32 wo = (qh[1].u[i] & 0xffff0000u) | (qh[0].u[i] >> 16);
        vTw[(dbase + 2 * i) * FB_VSTR + m] = we;
        vTw[(dbase + 2 * i + 1) * FB_VSTR + m] = wo;
      }
#pragma unroll
      for (int ct = 0; ct < 2; ++ct)
#pragma unroll
        for (int rt = 0; rt < 2; ++rt) {
          st[ct][rt] = __builtin_amdgcn_mfma_f32_16x16x32_bf16(qh[ct].v, ah[rt][kt].v, st[ct][rt], 0, 0, 0);
          st[ct][rt] = __builtin_amdgcn_mfma_f32_16x16x32_bf16(qh[ct].v, al[rt][kt].v, st[ct][rt], 0, 0, 0);
          st[ct][rt] = __builtin_amdgcn_mfma_f32_16x16x32_bf16(ql[ct].v, ah[rt][kt].v, st[ct][rt], 0, 0, 0);
        }
    }
#pragma unroll
    for (int ct = 0; ct < 2; ++ct)
#pragma unroll
      for (int rt = 0; rt < 2; ++rt)
        *(f32x4*)&sp[w][rt * 16 + m][ct * 16 + g * 4] = st[ct][rt];
    __syncthreads();
#pragma unroll
    for (int rep = 0; rep < 2; ++rep) {
      const int pp = tid + rep * 512;
      const int r = pp >> 5, c = pp & 31;
      float acc = 0.f;
#pragma unroll
      for (int ww = 0; ww < 8; ++ww) acc += sp[ww][r][c];
      ssum[r][c] = acc;
    }
    __syncthreads();
    f32x4 sv[2][2];
#pragma unroll
    for (int ct = 0; ct < 2; ++ct)
#pragma unroll
      for (int rt = 0; rt < 2; ++rt)
        sv[ct][rt] = *(const f32x4*)&ssum[rt * 16 + m][ct * 16 + g * 4];
    float mx0 = -1e30f, mx1 = -1e30f;
#pragma unroll
    for (int ct = 0; ct < 2; ++ct)
#pragma unroll
      for (int j = 0; j < 4; ++j) {
        mx0 = fmaxf(mx0, sv[ct][0][j]);
        mx1 = fmaxf(mx1, sv[ct][1][j]);
      }
    mx0 = fmaxf(mx0, __shfl_xor(mx0, 16));
    mx0 = fmaxf(mx0, __shfl_xor(mx0, 32));
    mx1 = fmaxf(mx1, __shfl_xor(mx1, 16));
    mx1 = fmaxf(mx1, __shfl_xor(mx1, 32));
    if (__any((mx0 > M0) | (mx1 > M1))) {
      const float nM0 = fmaxf(M0, mx0), nM1 = fmaxf(M1, mx1);
      const float c0 = __expf(M0 - nM0), c1 = __expf(M1 - nM1);
      M0 = nM0; M1 = nM1; L0 *= c0; L1 *= c1;
      f32x4 cr0, cr1;
#pragma unroll
      for (int j = 0; j < 4; ++j) { cr0[j] = __shfl(c0, g * 4 + j); cr1[j] = __shfl(c1, g * 4 + j); }
#pragma unroll
      for (int nt = 0; nt < 8; ++nt)
#pragma unroll
        for (int j = 0; j < 4; ++j) { oacc[0][nt][j] *= cr0[j]; oacc[1][nt][j] *= cr1[j]; }
    }
    f32x4 p00, p10, p01, p11;
#pragma unroll
    for (int j = 0; j < 4; ++j) {
      p00[j] = __expf(sv[0][0][j] - M0);
      p10[j] = __expf(sv[1][0][j] - M0);
      p01[j] = __expf(sv[0][1][j] - M1);
      p11[j] = __expf(sv[1][1][j] - M1);
    }
    float rs0 = 0.f, rs1 = 0.f;
#pragma unroll
    for (int j = 0; j < 4; ++j) { rs0 += p00[j] + p10[j]; rs1 += p01[j] + p11[j]; }
    rs0 += __shfl_xor(rs0, 16); rs0 += __shfl_xor(rs0, 32);
    rs1 += __shfl_xor(rs1, 16); rs1 += __shfl_xor(rs1, 32);
    L0 += rs0; L1 += rs1;
    FbFrag pa0, pa1;
#pragma unroll
    for (int j = 0; j < 4; ++j) {
      pa0.u[j] = fb_pack(p00[j], p10[j]);
      pa1.u[j] = fb_pack(p01[j], p11[j]);
    }
#pragma unroll
    for (int nt = 0; nt < 8; ++nt) {
      const u32* src = &vTw[(nt * 16 + m) * FB_VSTR + g * 4];
      FbFrag bqv;
      *(u32x2_t*)&bqv.u[0] = *(const u32x2_t*)&src[0];
      *(u32x2_t*)&bqv.u[2] = *(const u32x2_t*)&src[2];
      oacc[0][nt] = __builtin_amdgcn_mfma_f32_16x16x32_bf16(pa0.v, bqv.v, oacc[0][nt], 0, 0, 0);
      oacc[1][nt] = __builtin_amdgcn_mfma_f32_16x16x32_bf16(pa1.v, bqv.v, oacc[1][nt], 0, 0, 0);
    }
  }
  f32x4 i0, i1;
#pragma unroll
  for (int j = 0; j < 4; ++j) {
    i0[j] = 1.f / __shfl(L0, g * 4 + j);
    i1[j] = 1.f / __shfl(L1, g * 4 + j);
  }
#pragma unroll
  for (int mt = 0; mt < 2; ++mt)
#pragma unroll
    for (int nt = 0; nt < 8; ++nt)
#pragma unroll
      for (int j = 0; j < 4; ++j) {
        const int r = mt * 16 + g * 4 + j;
        const int dcol = dw + nt * 16 + m;
        Ob[(size_t)r * DD + dcol] = oacc[mt][nt][j] * (mt ? i1[j] : i0[j]);
      }
}

extern "C" void kernel_launch(void* const* d_in, const int* in_sizes, int n_in,
                              void* d_out, int out_size, void* d_ws, size_t ws_size,
                              hipStream_t stream) {
  const float* q = (const float*)d_in[0];
  const float* a = (const float*)d_in[1];
  float* o = (float*)d_out;
  if (ws_size >= WS_NEED) {
    char* ws = (char*)d_ws;
    u16* qh  = (u16*)(ws + WS_QH);
    u32* qt2 = (u32*)(ws + WS_QT2);
    prepass<<<NB * 64 * 16, 256, 0, stream>>>(q, qh, qt2);
    attn_main<<<NB * (SEQ / BM), 768, 0, stream>>>(a, qh, qt2, o);
  } else {
    attn_fb<<<NB * (SEQ / 32), 512, 0, stream>>>(q, a, o);
  }
  (void)in_sizes; (void)n_in; (void)out_size;
}

// Round 12
// 499.286 us; speedup vs baseline: 1.5621x; 1.5324x over previous
//
#include <hip/hip_runtime.h>
#include <stdint.h>

typedef short bf16x8 __attribute__((ext_vector_type(8)));
typedef _Float16 f16x8 __attribute__((ext_vector_type(8)));
typedef float f32x4 __attribute__((ext_vector_type(4)));
typedef unsigned int u32x2_t __attribute__((ext_vector_type(2)));
typedef unsigned int u32x4_t __attribute__((ext_vector_type(4)));
typedef unsigned int u32;
typedef unsigned short u16;
typedef unsigned char u8;
typedef unsigned long long u64;

#define NB  16
#define SEQ 2048
#define DD  1024
#define BM  32
#define KVB 32
#define NKB (SEQ / KVB)

// d_ws layout (bytes):
//   QF  [b][kb][sw][ct][kt][lane] f16 fragment-ordered Q     : 64 MB
//   QT2 [b][kb][d][16 u32] kv-pair-interleaved f16 Q^T tiles : 64 MB
#define WS_QF  0ULL
#define WS_QT2 (64ULL << 20)
#define WS_NEED (128ULL << 20)

union HF { u32 u[4]; u32x4_t u4; f16x8 v; };

__device__ __forceinline__ f32x4 z4() {
  f32x4 v; v[0] = 0.f; v[1] = 0.f; v[2] = 0.f; v[3] = 0.f; return v;
}
__device__ __forceinline__ float h16(float x) {
  return __uint_as_float((__float_as_uint(x) + 0x1000u) & 0xFFFFE000u);
}
__device__ __forceinline__ u32 packh(float a, float b) {
  auto t = __builtin_amdgcn_cvt_pkrtz(a, b);
  return *(u32*)&t;
}
__device__ __forceinline__ f32x4 mfma16(f16x8 a, f16x8 b, f32x4 c) {
  return __builtin_amdgcn_mfma_f32_16x16x32_f16(a, b, c, 0, 0, 0);
}
// LDS-ordering barrier only; VMEM loads stay in flight (no vmcnt drain).
__device__ __forceinline__ void wg_barrier() {
  asm volatile("s_waitcnt lgkmcnt(0)" ::: "memory");
  __builtin_amdgcn_s_barrier();
  asm volatile("" ::: "memory");
}

// ---------------- prepass: q -> QF (fragment-ordered) + QT2 (kb-blocked transposed) ----------------
__global__ __launch_bounds__(256)
void prepass(const float* __restrict__ Q, u32* __restrict__ QF, u32* __restrict__ QT2) {
  __shared__ u16 hl[32][72];
  const int t = threadIdx.x;
  const int bidx = (int)blockIdx.x;          // b*1024 + kvb*16 + db
  const int db = bidx & 15, kvb = (bidx >> 4) & 63, b = bidx >> 10;
  const int r = t >> 3, dcc = (t & 7) * 8;
  const int kv = kvb * 32 + r;
  const size_t row = (size_t)(b * SEQ + kv) * DD + db * 64 + dcc;
  f32x4 v0 = ((const f32x4*)(Q + row))[0];
  f32x4 v1 = ((const f32x4*)(Q + row))[1];
  float e[8] = { v0[0], v0[1], v0[2], v0[3], v1[0], v1[1], v1[2], v1[3] };
  u32x4_t hw;
#pragma unroll
  for (int j = 0; j < 4; ++j)
    hw[j] = packh(h16(e[2 * j]), h16(e[2 * j + 1]));
#pragma unroll
  for (int j = 0; j < 4; ++j) {
    hl[r][dcc + 2 * j]     = (u16)(hw[j] & 0xffffu);
    hl[r][dcc + 2 * j + 1] = (u16)(hw[j] >> 16);
  }
  __syncthreads();
  // QT2 write (transposed, (kv, kv+16) pair-interleaved)
  {
    const int d = t >> 2, i4 = (t & 3) * 4;
    u32x4_t w;
#pragma unroll
    for (int ii = 0; ii < 4; ++ii) {
      const int i = i4 + ii;
      w[ii] = (u32)hl[i][d] | ((u32)hl[i + 16][d] << 16);  // (kv0+i, kv0+16+i)
    }
    u32* dst = QT2 + (((size_t)(b * 64 + kvb) * 1024) + (db * 64 + d)) * 16 + i4;
    *(u32x4_t*)dst = w;
  }
  // QF write (fragment-ordered: [b][kb][sw][ct][kt][lane], 16B per lane)
  {
    const int ct  = t >> 7;
    const int ktl = (t >> 6) & 1;
    const int ln  = t & 63;
    const int m2  = ln & 15, g2 = ln >> 4;
    const int sw  = db >> 2;
    const int ktp = (db & 3) * 2;
    u32x4_t wf;
#pragma unroll
    for (int jj = 0; jj < 4; ++jj) {
      const int c0 = ktl * 32 + g2 * 8 + 2 * jj;
      wf[jj] = (u32)hl[ct * 16 + m2][c0] | ((u32)hl[ct * 16 + m2][c0 + 1] << 16);
    }
    u32* dstf = QF + ((((size_t)(b * 64 + kvb) * 4 + sw) * 2 + ct) * 8 + (ktp + ktl)) * 256 + ln * 4;
    *(u32x4_t*)dstf = wf;
  }
}

// ---------------- main: producer/consumer wave specialization (8 PV + 4 S waves) ----------------
__global__ __launch_bounds__(768, 3)
void attn_main(const float* __restrict__ Ag, const u32* __restrict__ QF,
               const u32* __restrict__ QT2, float* __restrict__ Og) {
  __shared__ alignas(16) float sp[2][4][32][36];   // [buf][sw][arow][kv] partial S^T (36864 B)
  __shared__ alignas(16) u32  Plds[2][32][20];     // [buf][arow][pair-word]           (5120 B)
  __shared__ alignas(16) float crow[2][32];        // per-row rescale factor
  __shared__ alignas(16) float Lrow[32];           // running denominators

  const int tid  = (int)threadIdx.x;
  const int w    = tid >> 6;
  const int lane = tid & 63;
  const int g    = lane >> 4;
  const int m    = lane & 15;

  // XCD chunk swizzle (bijective, 1024 = 8*128)
  const int p = (int)blockIdx.x;
  const int l = (p & 7) * 128 + (p >> 3);
  const int b = l >> 6;
  const int ablk = l & 63;

  const float* Abase = Ag + ((size_t)(b * SEQ + ablk * BM)) * DD;
  float*       Ob    = Og + ((size_t)(b * SEQ + ablk * BM)) * DD;

  if (w >= 8) {
    // ================= S waves (producers): wave sw covers d-chunk [256*sw, 256*sw+256) =================
    const int sw = w - 8;
    const u32* Qf = QF + (size_t)(b * 64) * 16384 + sw * 4096;

    f16x8 ah[2][8];
#pragma unroll
    for (int rt = 0; rt < 2; ++rt) {
#pragma unroll
      for (int kt = 0; kt < 8; ++kt) {
        const float* src = Abase + (size_t)(rt * 16 + m) * DD + sw * 256 + kt * 32 + g * 8;
        f32x4 v0 = ((const f32x4*)src)[0];
        f32x4 v1 = ((const f32x4*)src)[1];
        float e[8] = { v0[0], v0[1], v0[2], v0[3], v1[0], v1[1], v1[2], v1[3] };
        HF fh;
#pragma unroll
        for (int j = 0; j < 4; ++j) fh.u[j] = packh(h16(e[2 * j]), h16(e[2 * j + 1]));
        ah[rt][kt] = fh.v;
      }
    }

    HF q[2][8];
    auto LOADQ = [&](int kbi) {
#pragma unroll
      for (int ct = 0; ct < 2; ++ct)
#pragma unroll
        for (int kt = 0; kt < 8; ++kt)
          q[ct][kt].u4 = *(const u32x4_t*)(Qf + (size_t)kbi * 16384 + ct * 2048 + kt * 256 + lane * 4);
    };
    auto SSTEP = [&](int buf) {
      f32x4 st[2][2];
#pragma unroll
      for (int ct = 0; ct < 2; ++ct)
#pragma unroll
        for (int rt = 0; rt < 2; ++rt) st[ct][rt] = z4();
#pragma unroll
      for (int kt = 0; kt < 8; ++kt)
#pragma unroll
        for (int ct = 0; ct < 2; ++ct) {
          st[ct][0] = mfma16(q[ct][kt].v, ah[0][kt], st[ct][0]);
          st[ct][1] = mfma16(q[ct][kt].v, ah[1][kt], st[ct][1]);
        }
#pragma unroll
      for (int ct = 0; ct < 2; ++ct)
#pragma unroll
        for (int rt = 0; rt < 2; ++rt)
          *(f32x4*)&sp[buf][sw][rt * 16 + m][ct * 16 + g * 4] = st[ct][rt];
    };

    LOADQ(0);
    SSTEP(0);
    LOADQ(1);
    wg_barrier();                       // #0

#pragma unroll 1
    for (int kb = 0; kb < NKB; ++kb) {
      if (kb + 1 < NKB) {
        SSTEP((kb + 1) & 1);
        if (kb + 2 < NKB) LOADQ(kb + 2);
      }
      wg_barrier();                     // #kb+1
    }
  } else {
    // ================= PV waves (consumers): wave w owns O d-chunk [128*w, 128*w+128) =================
    const int dw = w * 128;
    const int srow = 4 * w + (lane >> 3);   // softmax row (lanes<32)
    const int qc   = lane & 7;              // softmax kv-quad (lanes<32)
    const u32* Vb = QT2 + (size_t)(b * 64) * 16384 + (size_t)(dw + m) * 16 + g * 4;

    f32x4 oacc[2][8];
#pragma unroll
    for (int mt = 0; mt < 2; ++mt)
#pragma unroll
      for (int nt = 0; nt < 8; ++nt) oacc[mt][nt] = z4();
    float M = -1e30f, L = 0.f;
    u32x4_t bq[8];

    auto PV = [&](int C) {
      f32x4 cr0 = *(const f32x4*)&crow[C][g * 4];
      f32x4 cr1 = *(const f32x4*)&crow[C][16 + g * 4];
      HF pa0, pa1;
      pa0.u4 = *(const u32x4_t*)&Plds[C][m][g * 4];
      pa1.u4 = *(const u32x4_t*)&Plds[C][16 + m][g * 4];
      bool nr = (cr0[0] != 1.f) | (cr0[1] != 1.f) | (cr0[2] != 1.f) | (cr0[3] != 1.f) |
                (cr1[0] != 1.f) | (cr1[1] != 1.f) | (cr1[2] != 1.f) | (cr1[3] != 1.f);
      if (__any(nr)) {
#pragma unroll
        for (int nt = 0; nt < 8; ++nt)
#pragma unroll
          for (int j = 0; j < 4; ++j) {
            oacc[0][nt][j] *= cr0[j];
            oacc[1][nt][j] *= cr1[j];
          }
      }
#pragma unroll
      for (int nt = 0; nt < 8; ++nt) {
        HF bqv; bqv.u4 = bq[nt];
        oacc[0][nt] = mfma16(pa0.v, bqv.v, oacc[0][nt]);
        oacc[1][nt] = mfma16(pa1.v, bqv.v, oacc[1][nt]);
      }
    };

    wg_barrier();                       // #0

#pragma unroll 1
    for (int kb = 0; kb < NKB; ++kb) {
      const int A = kb & 1;

      if (kb > 0) PV(A ^ 1);

      const u32* vrow = Vb + (size_t)kb * 16384;
#pragma unroll
      for (int nt = 0; nt < 8; ++nt)
        bq[nt] = *(const u32x4_t*)(vrow + nt * 256);

      if (lane < 32) {
        f32x4 s4 = *(const f32x4*)&sp[A][0][srow][qc * 4];
#pragma unroll
        for (int sw2 = 1; sw2 < 4; ++sw2) {
          f32x4 t = *(const f32x4*)&sp[A][sw2][srow][qc * 4];
          s4 += t;
        }
        float mq = fmaxf(fmaxf(s4[0], s4[1]), fmaxf(s4[2], s4[3]));
        mq = fmaxf(mq, __shfl_xor(mq, 1));
        mq = fmaxf(mq, __shfl_xor(mq, 2));
        mq = fmaxf(mq, __shfl_xor(mq, 4));
        const float Mn = fmaxf(M, mq);
        const float c = __expf(M - Mn);     // == 1.0 exactly when M unchanged
        const float p0 = __expf(s4[0] - Mn);
        const float p1 = __expf(s4[1] - Mn);
        const float p2 = __expf(s4[2] - Mn);
        const float p3 = __expf(s4[3] - Mn);
        float rq = (p0 + p1) + (p2 + p3);
        rq += __shfl_xor(rq, 1);
        rq += __shfl_xor(rq, 2);
        rq += __shfl_xor(rq, 4);
        L = L * c + rq;
        M = Mn;
        const float q0 = __shfl_xor(p0, 4);
        const float q1 = __shfl_xor(p1, 4);
        const float q2 = __shfl_xor(p2, 4);
        const float q3 = __shfl_xor(p3, 4);
        if (qc < 4) {   // pack (kv, kv+16) pairs -> matches QT2 words
          u32x4_t wv;
          wv[0] = packh(p0, q0); wv[1] = packh(p1, q1);
          wv[2] = packh(p2, q2); wv[3] = packh(p3, q3);
          *(u32x4_t*)&Plds[A][srow][qc * 4] = wv;
        }
        if (qc == 0) { crow[A][srow] = c; Lrow[srow] = L; }
      }

      wg_barrier();                     // #kb+1
    }

    // drain last PV, then normalize and store
    PV((NKB - 1) & 1);

    f32x4 L0v = *(const f32x4*)&Lrow[g * 4];
    f32x4 L1v = *(const f32x4*)&Lrow[16 + g * 4];
    f32x4 i0, i1;
#pragma unroll
    for (int j = 0; j < 4; ++j) { i0[j] = 1.f / L0v[j]; i1[j] = 1.f / L1v[j]; }
#pragma unroll
    for (int mt = 0; mt < 2; ++mt)
#pragma unroll
      for (int nt = 0; nt < 8; ++nt)
#pragma unroll
        for (int j = 0; j < 4; ++j) {
          const int r  = mt * 16 + g * 4 + j;
          const int dcol = dw + nt * 16 + m;
          Ob[(size_t)r * DD + dcol] = oacc[mt][nt][j] * (mt ? i1[j] : i0[j]);
        }
  }
}

// ---------------- fallback (round-2 kernel, proven) ----------------
#define FB_VSTR 18
__device__ __forceinline__ u32 fb_rn16(u32 bb) { return (bb + 0x8000u) & 0xffff0000u; }
__device__ __forceinline__ u32 fb_pack(float x0, float x1) {
  return fb_rn16(__float_as_uint(x1)) | (fb_rn16(__float_as_uint(x0)) >> 16);
}
union FbFrag { u32 u[4]; u32x4_t u4; bf16x8 v; };
__device__ __forceinline__ void fb_cvt(const float* x, FbFrag& fh, FbFrag& fl) {
#pragma unroll
  for (int i = 0; i < 4; ++i) {
    float x0 = x[2 * i], x1 = x[2 * i + 1];
    u32 h0 = fb_rn16(__float_as_uint(x0));
    u32 h1 = fb_rn16(__float_as_uint(x1));
    fh.u[i] = h1 | (h0 >> 16);
    fl.u[i] = fb_pack(x0 - __uint_as_float(h0), x1 - __uint_as_float(h1));
  }
}

__global__ __launch_bounds__(512, 2)
void attn_fb(const float* __restrict__ Qg, const float* __restrict__ Ag,
             float* __restrict__ Og) {
  __shared__ u32 vT[8][128 * FB_VSTR];
  __shared__ float sp[8][32][36];
  __shared__ float ssum[32][36];
  const int tid = threadIdx.x, w = tid >> 6, lane = tid & 63, g = lane >> 4, m = lane & 15;
  const int bid = (int)blockIdx.x, b = bid >> 6, ablk = bid & 63, dw = w * 128;
  const float* Qb = Qg + (size_t)b * SEQ * DD;
  const float* Abase = Ag + ((size_t)b * SEQ + ablk * 32) * DD;
  float* Ob = Og + ((size_t)b * SEQ + ablk * 32) * DD;
  FbFrag ah[2][4], al[2][4];
#pragma unroll
  for (int rt = 0; rt < 2; ++rt)
#pragma unroll
    for (int kt = 0; kt < 4; ++kt) {
      const float* src = Abase + (size_t)(rt * 16 + m) * DD + dw + kt * 32 + g * 8;
      f32x4 v0 = ((const f32x4*)src)[0], v1 = ((const f32x4*)src)[1];
      float x[8];
#pragma unroll
      for (int i = 0; i < 4; ++i) { x[i] = v0[i]; x[4 + i] = v1[i]; }
      fb_cvt(x, ah[rt][kt], al[rt][kt]);
    }
  f32x4 oacc[2][8];
#pragma unroll
  for (int mt = 0; mt < 2; ++mt)
#pragma unroll
    for (int nt = 0; nt < 8; ++nt) oacc[mt][nt] = z4();
  float M0 = -1e30f, M1 = -1e30f, L0 = 0.f, L1 = 0.f;
  u32* vTw = &vT[w][0];
#pragma unroll 1
  for (int kb = 0; kb < NKB; ++kb) {
    const int kv0 = kb * KVB;
    f32x4 st[2][2];
#pragma unroll
    for (int ct = 0; ct < 2; ++ct)
#pragma unroll
      for (int rt = 0; rt < 2; ++rt) st[ct][rt] = z4();
#pragma unroll
    for (int kt = 0; kt < 4; ++kt) {
      FbFrag qh[2], ql[2];
#pragma unroll
      for (int kvt = 0; kvt < 2; ++kvt) {
        const float* src = Qb + (size_t)(kv0 + kvt * 16 + m) * DD + dw + kt * 32 + g * 8;
        f32x4 v0 = ((const f32x4*)src)[0], v1 = ((const f32x4*)src)[1];
        float x[8];
#pragma unroll
        for (int i = 0; i < 4; ++i) { x[i] = v0[i]; x[4 + i] = v1[i]; }
        fb_cvt(x, qh[kvt], ql[kvt]);
      }
      const int dbase = kt * 32 + g * 8;
#pragma unroll
      for (int i = 0; i < 4; ++i) {
        u32 we = (qh[1].u[i] << 16) | (qh[0].u[i] & 0xffffu);
        u32 wo = (qh[1].u[i] & 0xffff0000u) | (qh[0].u[i] >> 16);
        vTw[(dbase + 2 * i) * FB_VSTR + m] = we;
        vTw[(dbase + 2 * i + 1) * FB_VSTR + m] = wo;
      }
#pragma unroll
      for (int ct = 0; ct < 2; ++ct)
#pragma unroll
        for (int rt = 0; rt < 2; ++rt) {
          st[ct][rt] = __builtin_amdgcn_mfma_f32_16x16x32_bf16(qh[ct].v, ah[rt][kt].v, st[ct][rt], 0, 0, 0);
          st[ct][rt] = __builtin_amdgcn_mfma_f32_16x16x32_bf16(qh[ct].v, al[rt][kt].v, st[ct][rt], 0, 0, 0);
          st[ct][rt] = __builtin_amdgcn_mfma_f32_16x16x32_bf16(ql[ct].v, ah[rt][kt].v, st[ct][rt], 0, 0, 0);
        }
    }
#pragma unroll
    for (int ct = 0; ct < 2; ++ct)
#pragma unroll
      for (int rt = 0; rt < 2; ++rt)
        *(f32x4*)&sp[w][rt * 16 + m][ct * 16 + g * 4] = st[ct][rt];
    __syncthreads();
#pragma unroll
    for (int rep = 0; rep < 2; ++rep) {
      const int pp = tid + rep * 512;
      const int r = pp >> 5, c = pp & 31;
      float acc = 0.f;
#pragma unroll
      for (int ww = 0; ww < 8; ++ww) acc += sp[ww][r][c];
      ssum[r][c] = acc;
    }
    __syncthreads();
    f32x4 sv[2][2];
#pragma unroll
    for (int ct = 0; ct < 2; ++ct)
#pragma unroll
      for (int rt = 0; rt < 2; ++rt)
        sv[ct][rt] = *(const f32x4*)&ssum[rt * 16 + m][ct * 16 + g * 4];
    float mx0 = -1e30f, mx1 = -1e30f;
#pragma unroll
    for (int ct = 0; ct < 2; ++ct)
#pragma unroll
      for (int j = 0; j < 4; ++j) {
        mx0 = fmaxf(mx0, sv[ct][0][j]);
        mx1 = fmaxf(mx1, sv[ct][1][j]);
      }
    mx0 = fmaxf(mx0, __shfl_xor(mx0, 16));
    mx0 = fmaxf(mx0, __shfl_xor(mx0, 32));
    mx1 = fmaxf(mx1, __shfl_xor(mx1, 16));
    mx1 = fmaxf(mx1, __shfl_xor(mx1, 32));
    if (__any((mx0 > M0) | (mx1 > M1))) {
      const float nM0 = fmaxf(M0, mx0), nM1 = fmaxf(M1, mx1);
      const float c0 = __expf(M0 - nM0), c1 = __expf(M1 - nM1);
      M0 = nM0; M1 = nM1; L0 *= c0; L1 *= c1;
      f32x4 cr0, cr1;
#pragma unroll
      for (int j = 0; j < 4; ++j) { cr0[j] = __shfl(c0, g * 4 + j); cr1[j] = __shfl(c1, g * 4 + j); }
#pragma unroll
      for (int nt = 0; nt < 8; ++nt)
#pragma unroll
        for (int j = 0; j < 4; ++j) { oacc[0][nt][j] *= cr0[j]; oacc[1][nt][j] *= cr1[j]; }
    }
    f32x4 p00, p10, p01, p11;
#pragma unroll
    for (int j = 0; j < 4; ++j) {
      p00[j] = __expf(sv[0][0][j] - M0);
      p10[j] = __expf(sv[1][0][j] - M0);
      p01[j] = __expf(sv[0][1][j] - M1);
      p11[j] = __expf(sv[1][1][j] - M1);
    }
    float rs0 = 0.f, rs1 = 0.f;
#pragma unroll
    for (int j = 0; j < 4; ++j) { rs0 += p00[j] + p10[j]; rs1 += p01[j] + p11[j]; }
    rs0 += __shfl_xor(rs0, 16); rs0 += __shfl_xor(rs0, 32);
    rs1 += __shfl_xor(rs1, 16); rs1 += __shfl_xor(rs1, 32);
    L0 += rs0; L1 += rs1;
    FbFrag pa0, pa1;
#pragma unroll
    for (int j = 0; j < 4; ++j) {
      pa0.u[j] = fb_pack(p00[j], p10[j]);
      pa1.u[j] = fb_pack(p01[j], p11[j]);
    }
#pragma unroll
    for (int nt = 0; nt < 8; ++nt) {
      const u32* src = &vTw[(nt * 16 + m) * FB_VSTR + g * 4];
      FbFrag bqv;
      *(u32x2_t*)&bqv.u[0] = *(const u32x2_t*)&src[0];
      *(u32x2_t*)&bqv.u[2] = *(const u32x2_t*)&src[2];
      oacc[0][nt] = __builtin_amdgcn_mfma_f32_16x16x32_bf16(pa0.v, bqv.v, oacc[0][nt], 0, 0, 0);
      oacc[1][nt] = __builtin_amdgcn_mfma_f32_16x16x32_bf16(pa1.v, bqv.v, oacc[1][nt], 0, 0, 0);
    }
  }
  f32x4 i0, i1;
#pragma unroll
  for (int j = 0; j < 4; ++j) {
    i0[j] = 1.f / __shfl(L0, g * 4 + j);
    i1[j] = 1.f / __shfl(L1, g * 4 + j);
  }
#pragma unroll
  for (int mt = 0; mt < 2; ++mt)
#pragma unroll
    for (int nt = 0; nt < 8; ++nt)
#pragma unroll
      for (int j = 0; j < 4; ++j) {
        const int r = mt * 16 + g * 4 + j;
        const int dcol = dw + nt * 16 + m;
        Ob[(size_t)r * DD + dcol] = oacc[mt][nt][j] * (mt ? i1[j] : i0[j]);
      }
}

extern "C" void kernel_launch(void* const* d_in, const int* in_sizes, int n_in,
                              void* d_out, int out_size, void* d_ws, size_t ws_size,
                              hipStream_t stream) {
  const float* q = (const float*)d_in[0];
  const float* a = (const float*)d_in[1];
  float* o = (float*)d_out;
  if (ws_size >= WS_NEED) {
    char* ws = (char*)d_ws;
    u32* qf  = (u32*)(ws + WS_QF);
    u32* qt2 = (u32*)(ws + WS_QT2);
    prepass<<<NB * 64 * 16, 256, 0, stream>>>(q, qf, qt2);
    attn_main<<<NB * (SEQ / BM), 768, 0, stream>>>(a, qf, qt2, o);
  } else {
    attn_fb<<<NB * (SEQ / 32), 512, 0, stream>>>(q, a, o);
  }
  (void)in_sizes; (void)n_in; (void)out_size;
}